// Round 4
// baseline (529.559 us; speedup 1.0000x reference)
//
#include <hip/hip_runtime.h>
#include <cstdint>
#include <cstddef>

#define BB 4
#define NN 16384
#define PRE 4096
#define POST 512
#define CAP 32
#define SELCAP 8192
#define BINS 8192  // top-13 bits of f32 ordinal

typedef unsigned short u16;
typedef unsigned int u32;
typedef unsigned long long u64;

// monotone map: f32 bits -> u32 ordinal preserving float order
__device__ __forceinline__ u32 ord32(float f) {
  u32 u = __builtin_bit_cast(u32, f);
  return (u & 0x80000000u) ? ~u : (u | 0x80000000u);
}

// ---- K1: per-batch score->ord, LDS histogram, threshold bin B*; zero selctr/cnt/hasadj ----
__global__ __launch_bounds__(1024) void histbstar_kernel(const float* __restrict__ cls,
                                                         u32* __restrict__ ord,
                                                         u32* __restrict__ bstar,
                                                         u32* __restrict__ selctr,
                                                         u32* __restrict__ cnt,
                                                         u64* __restrict__ hasadj) {
  __shared__ u32 hist[BINS];   // 32 KB
  __shared__ u32 orig[1024];
  __shared__ u32 bufA[1024];
  __shared__ u32 bufB[1024];   // +12 KB
  __shared__ int bs;
  const int b = blockIdx.x, t = threadIdx.x;
  for (int p = t; p < BINS; p += 1024) hist[p] = 0u;
  if (t == 0) { bs = 0; selctr[b] = 0u; }
  if (t < 64) hasadj[(b << 6) + t] = 0ull;
  for (int p = t; p < PRE; p += 1024) cnt[(b << 12) + p] = 0u;
  __syncthreads();
  const float* c = cls + (size_t)b * NN * 3;
  for (int n = t; n < NN; n += 1024) {
    float s = fmaxf(fmaxf(c[n * 3], c[n * 3 + 1]), c[n * 3 + 2]);
    u32 o = ord32(s);
    ord[b * NN + n] = o;
    atomicAdd(&hist[o >> 19], 1u);
  }
  __syncthreads();
  u32 s = 0;
#pragma unroll
  for (int j = 0; j < 8; ++j) s += hist[t * 8 + j];
  orig[t] = s;
  bufA[t] = s;
  __syncthreads();
  // inclusive suffix scan over 1024 chunk totals (Hillis-Steele, double buffer)
  u32* src = bufA;
  u32* dst = bufB;
  for (int off = 1; off < 1024; off <<= 1) {
    u32 v = src[t] + ((t + off < 1024) ? src[t + off] : 0u);
    dst[t] = v;
    __syncthreads();
    u32* tmp = src; src = dst; dst = tmp;
  }
  u32 running = src[t] - orig[t];  // count of items in bins above this chunk
  for (int j = 7; j >= 0; --j) {
    u32 v = hist[t * 8 + j];
    u32 nr = running + v;
    if (nr >= (u32)PRE && running < (u32)PRE) bs = t * 8 + j;  // unique crossing
    running = nr;
  }
  __syncthreads();
  if (t == 0) bstar[b] = (u32)bs;
}

// ---- K2: compact candidates (bin >= B*) into unordered per-batch key list ----
__global__ void compact_kernel(const u32* __restrict__ ord, const u32* __restrict__ bstar,
                               u32* __restrict__ selctr, u64* __restrict__ candkey) {
  int g = blockIdx.x * 256 + threadIdx.x;
  if (g >= BB * NN) return;
  int b = g >> 14;
  u32 o = ord[g];
  if ((o >> 19) >= bstar[b]) {
    u32 pos = atomicAdd(&selctr[b], 1u);
    if (pos < SELCAP)
      candkey[(size_t)b * SELCAP + pos] = ((u64)o << 14) | (u64)(NN - 1 - (g & (NN - 1)));
  }
}

// ---- K3: rank-by-counting (keys unique) + fused geometry gather at rank position ----
__global__ __launch_bounds__(256) void rankgeom_kernel(
    const float* __restrict__ box, const float* __restrict__ cls,
    const u32* __restrict__ selctr, const u64* __restrict__ candkey,
    u32* __restrict__ sidx,
    float* __restrict__ gx1, float* __restrict__ gx2,
    float* __restrict__ gy1, float* __restrict__ gy2,
    float* __restrict__ garea, float* __restrict__ gsc, u32* __restrict__ glab) {
  const int blk = blockIdx.x;
  const int b = blk >> 5, u = blk & 31;  // 32 blocks x 256 threads = 8192 >= C
  const int t = threadIdx.x;
  u32 C = selctr[b];
  if (C > SELCAP) C = SELCAP;
  const int cand = u * 256 + t;
  if (cand >= (int)C) return;
  const u64* __restrict__ ck = candkey + (size_t)b * SELCAP;
  const u64 mykey = ck[cand];
  u32 r = 0;
  int k = 0;
  const int C4 = (int)C & ~7;
  for (; k < C4; k += 8) {
    // k is wave-uniform -> scalar-pipe loads; keys are L1/L2-hot (34 KB/batch)
    u64 k0 = ck[k], k1 = ck[k + 1], k2 = ck[k + 2], k3 = ck[k + 3];
    u64 k4 = ck[k + 4], k5 = ck[k + 5], k6 = ck[k + 6], k7 = ck[k + 7];
    r += (u32)(k0 > mykey) + (u32)(k1 > mykey) + (u32)(k2 > mykey) + (u32)(k3 > mykey);
    r += (u32)(k4 > mykey) + (u32)(k5 > mykey) + (u32)(k6 > mykey) + (u32)(k7 > mykey);
  }
  for (; k < (int)C; ++k) r += (u32)(ck[k] > mykey);
  if (r >= (u32)PRE) return;
  const int idx = (NN - 1) - (int)(mykey & 0x3FFFull);
  const int g = (b << 12) + (int)r;
  sidx[g] = (u32)idx;
  const float* bp = box + ((size_t)(b << 14) + idx) * 7;
  float x = bp[0], y = bp[1];
  float dx = bp[3], dy = bp[4];
  gx1[g] = x - dx * 0.5f;
  gx2[g] = x + dx * 0.5f;
  gy1[g] = y - dy * 0.5f;
  gy2[g] = y + dy * 0.5f;
  garea[g] = dx * dy;
  const float* cp = cls + ((size_t)(b << 14) + idx) * 3;
  float f0 = cp[0], f1 = cp[1], f2 = cp[2];
  int lab = 0;
  float best = f0;
  if (f1 > best) { best = f1; lab = 1; }
  if (f2 > best) { best = f2; lab = 2; }
  gsc[g] = best;
  glab[g] = (u32)lab;
}

// ---- K4: sparse suppression graph (i<j pairs with IoU>0.8) ----
__global__ void pairs_kernel(const float* __restrict__ gx1, const float* __restrict__ gx2,
                             const float* __restrict__ gy1, const float* __restrict__ gy2,
                             const float* __restrict__ garea,
                             u32* __restrict__ cnt, u32* __restrict__ adj,
                             u64* __restrict__ hasadj) {
  int bid = blockIdx.x;
  int b = bid >> 12;
  int r = bid & 4095;
  int ti = r >> 6, tj = r & 63;
  if (tj < ti) return;  // upper triangle of 64x64 tiles only
  int tid = threadIdx.x;
#pragma unroll
  for (int m = 0; m < 16; ++m) {
    int pid = tid + 256 * m;
    int il = pid >> 6, jl = pid & 63;
    int i = ti * 64 + il, j = tj * 64 + jl;
    if (j <= i) continue;
    int gi = (b << 12) + i, gj = (b << 12) + j;
    float ix = fminf(gx2[gi], gx2[gj]) - fmaxf(gx1[gi], gx1[gj]);
    ix = fmaxf(ix, 0.0f);
    float iy = fminf(gy2[gi], gy2[gj]) - fmaxf(gy1[gi], gy1[gj]);
    iy = fmaxf(iy, 0.0f);
    float inter = ix * iy;
    float denom = ((garea[gi] + garea[gj]) - inter) + 1e-6f;  // np op order
    float iou = inter / denom;                                // IEEE f32 div
    if (iou > 0.8f) {
      u32 pos = atomicAdd(&cnt[gi], 1u);
      if (pos < CAP) adj[(size_t)gi * CAP + pos] = (u32)j;
      if (pos == 0u) atomicOr(&hasadj[(b << 6) + (i >> 6)], 1ull << (i & 63));
    }
  }
}

// ---- K5: sequential NMS scan (lane 0) + all outputs (f32) ----
__global__ __launch_bounds__(256) void nms_kernel(
    const float* __restrict__ box, const float* __restrict__ gt,
    const u32* __restrict__ sidx, const float* __restrict__ gsc,
    const u32* __restrict__ glab, const u32* __restrict__ cnt,
    const u32* __restrict__ adj, const u64* __restrict__ hasadj,
    float* __restrict__ out) {
  __shared__ u64 sval[64];
  __shared__ u64 shadj[64];
  __shared__ u16 ssel[POST];
  __shared__ u16 skeep[POST];
  const int b = blockIdx.x, tid = threadIdx.x;
  if (tid < 64) {
    sval[tid] = ~0ull;
    shadj[tid] = hasadj[(b << 6) + tid];
  }
  __syncthreads();
  if (tid == 0) {
    int t = 0, wi = 0;
    u64 cw = sval[0], ha = shadj[0];
    while (t < POST) {
      if (cw == 0ull) {
        ++wi;
        if (wi == 64) break;
        cw = sval[wi];
        ha = shadj[wi];
        continue;
      }
      int bit = __ffsll((unsigned long long)cw) - 1;
      cw &= cw - 1;  // consume lowest set bit (= argmax(valid))
      int i = (wi << 6) + bit;
      ssel[t] = (u16)i;
      skeep[t] = 1;
      if ((ha >> bit) & 1ull) {  // rare: this box suppresses someone
        int c = (int)cnt[(b << 12) + i];
        if (c > CAP) c = CAP;
        for (int k2 = 0; k2 < c; ++k2) {
          u32 j = adj[((size_t)((b << 12) + i)) * CAP + k2];  // all j > i, j < 4096
          int wj = (int)(j >> 6);
          u64 mask = ~(1ull << (j & 63u));
          if (wj == wi) cw &= mask;
          else sval[wj] &= mask;
        }
      }
      ++t;
    }
    for (; t < POST; ++t) { ssel[t] = 0; skeep[t] = 0; }
  }
  __syncthreads();

  float* rois = out;                  // B*POST*7
  float* rsc  = out + BB * POST * 7;  // B*POST
  float* rlb  = rsc + BB * POST;      // B*POST
  float* rct  = rlb + BB * POST;      // B*POST*8

  const float TWO_PI_F = 6.283185307179586f;
  const float PI_F = 3.14159265358979323846f;
  const float HALF_PI_F = 1.5707963267948966f;
  const float THREE_HALF_PI_F = 4.71238898038469f;

  for (int t = tid; t < POST; t += 256) {
    int i = ssel[t];
    int kp = skeep[t];
    int g = (b << 12) + i;
    u32 idx = sidx[g];
    const float* bp = box + ((size_t)(b << 14) + idx) * 7;
    float bx[7];
#pragma unroll
    for (int d = 0; d < 7; ++d) bx[d] = kp ? bp[d] : 0.0f;
    float* ro = rois + ((size_t)b * POST + t) * 7;
#pragma unroll
    for (int d = 0; d < 7; ++d) ro[d] = bx[d];
    rsc[b * POST + t] = kp ? gsc[g] : 0.0f;
    rlb[b * POST + t] = (float)((kp ? (int)glab[g] : 0) + 1);

    // canonical transform in f32, matching np op order
    const float* gp = gt + ((size_t)b * POST + t) * 8;
    float g0 = gp[0], g1 = gp[1], g2 = gp[2], g6 = gp[6];
    float rr = fmodf(bx[6], TWO_PI_F);
    if (rr < 0.0f) rr += TWO_PI_F;
    float xyz0 = g0 - bx[0], xyz1 = g1 - bx[1], xyz2 = g2 - bx[2];
    float heading = g6 - rr;
    float aa = -rr;
    float cc = cosf(aa), s2 = sinf(aa);
    float nx = xyz0 * cc - xyz1 * s2;
    float ny = xyz0 * s2 + xyz1 * cc;
    float h = fmodf(heading, TWO_PI_F);
    if (h < 0.0f) h += TWO_PI_F;
    bool opp = (h > HALF_PI_F) && (h < THREE_HALF_PI_F);
    if (opp) {
      h = fmodf(h + PI_F, TWO_PI_F);
      if (h < 0.0f) h += TWO_PI_F;
    }
    if (h > PI_F) h -= TWO_PI_F;
    h = fminf(fmaxf(h, -HALF_PI_F), HALF_PI_F);

    float* co = rct + ((size_t)b * POST + t) * 8;
    co[0] = nx;
    co[1] = ny;
    co[2] = xyz2;
    co[3] = gp[3];
    co[4] = gp[4];
    co[5] = gp[5];
    co[6] = h;
    co[7] = gp[7];
  }
}

extern "C" void kernel_launch(void* const* d_in, const int* in_sizes, int n_in,
                              void* d_out, int out_size, void* d_ws, size_t ws_size,
                              hipStream_t stream) {
  const float* box = (const float*)d_in[0];  // (B,N,7) f32
  const float* cls = (const float*)d_in[1];  // (B,N,3) f32
  const float* gt  = (const float*)d_in[2];  // (B,POST,8) f32
  float* out = (float*)d_out;                // 34816 f32, concat in return order

  char* ws = (char*)d_ws;
  size_t off = 0;
  auto alloc = [&](size_t bytes) -> void* {
    void* p = ws + off;
    off += (bytes + 255) & ~(size_t)255;
    return p;
  };
  u32* ord     = (u32*)alloc((size_t)BB * NN * 4);        // 256 KB
  u32* bstar   = (u32*)alloc((size_t)BB * 4);
  u32* selctr  = (u32*)alloc((size_t)BB * 4);
  u64* candkey = (u64*)alloc((size_t)BB * SELCAP * 8);    // 256 KB
  u32* sidx    = (u32*)alloc((size_t)BB * PRE * 4);
  float* gx1   = (float*)alloc((size_t)BB * PRE * 4);
  float* gx2   = (float*)alloc((size_t)BB * PRE * 4);
  float* gy1   = (float*)alloc((size_t)BB * PRE * 4);
  float* gy2   = (float*)alloc((size_t)BB * PRE * 4);
  float* garea = (float*)alloc((size_t)BB * PRE * 4);
  float* gsc   = (float*)alloc((size_t)BB * PRE * 4);
  u32* glab    = (u32*)alloc((size_t)BB * PRE * 4);
  u32* cnt     = (u32*)alloc((size_t)BB * PRE * 4);
  u64* hasadj  = (u64*)alloc((size_t)BB * 64 * 8);
  u32* adj     = (u32*)alloc((size_t)BB * PRE * CAP * 4);  // 2 MB

  hipLaunchKernelGGL(histbstar_kernel, dim3(BB), dim3(1024), 0, stream,
                     cls, ord, bstar, selctr, cnt, hasadj);
  hipLaunchKernelGGL(compact_kernel, dim3(BB * NN / 256), dim3(256), 0, stream,
                     ord, bstar, selctr, candkey);
  hipLaunchKernelGGL(rankgeom_kernel, dim3(BB * 32), dim3(256), 0, stream,
                     box, cls, selctr, candkey, sidx, gx1, gx2, gy1, gy2, garea, gsc, glab);
  hipLaunchKernelGGL(pairs_kernel, dim3(BB * 64 * 64), dim3(256), 0, stream,
                     gx1, gx2, gy1, gy2, garea, cnt, adj, hasadj);
  hipLaunchKernelGGL(nms_kernel, dim3(BB), dim3(256), 0, stream,
                     box, gt, sidx, gsc, glab, cnt, adj, hasadj, out);
}

// Round 5
// 299.076 us; speedup vs baseline: 1.7706x; 1.7706x over previous
//
#include <hip/hip_runtime.h>
#include <cstdint>
#include <cstddef>

#define BB 4
#define NN 16384
#define PRE 4096
#define POST 512
#define CAP 32
#define SELCAP 6144   // C = 4096 + (one 13-bit bin ~ 500) << 6144
#define BINS 8192     // top-13 bits of f32 ordinal
#define NTILE 64      // 64 tiles of 64 boxes
#define NTRI 2080     // 64*65/2 upper-tri tiles

typedef unsigned short u16;
typedef unsigned int u32;
typedef unsigned long long u64;

// monotone map: f32 bits -> u32 ordinal preserving float order
__device__ __forceinline__ u32 ord32(float f) {
  u32 u = __builtin_bit_cast(u32, f);
  return (u & 0x80000000u) ? ~u : (u | 0x80000000u);
}

// ---- K1: per-batch score->ord, LDS histogram, threshold bin B*; zero selctr/cnt/hasadj ----
__global__ __launch_bounds__(1024) void histbstar_kernel(const float* __restrict__ cls,
                                                         u32* __restrict__ ord,
                                                         u32* __restrict__ bstar,
                                                         u32* __restrict__ selctr,
                                                         u32* __restrict__ cnt,
                                                         u64* __restrict__ hasadj) {
  __shared__ u32 hist[BINS];   // 32 KB
  __shared__ u32 orig[1024];
  __shared__ u32 bufA[1024];
  __shared__ u32 bufB[1024];   // +12 KB
  __shared__ int bs;
  const int b = blockIdx.x, t = threadIdx.x;
  for (int p = t; p < BINS; p += 1024) hist[p] = 0u;
  if (t == 0) { bs = 0; selctr[b] = 0u; }
  if (t < 64) hasadj[(b << 6) + t] = 0ull;
  for (int p = t; p < PRE; p += 1024) cnt[(b << 12) + p] = 0u;
  __syncthreads();
  const float* c = cls + (size_t)b * NN * 3;
  for (int n = t; n < NN; n += 1024) {
    float s = fmaxf(fmaxf(c[n * 3], c[n * 3 + 1]), c[n * 3 + 2]);
    u32 o = ord32(s);
    ord[b * NN + n] = o;
    atomicAdd(&hist[o >> 19], 1u);
  }
  __syncthreads();
  u32 s = 0;
#pragma unroll
  for (int j = 0; j < 8; ++j) s += hist[t * 8 + j];
  orig[t] = s;
  bufA[t] = s;
  __syncthreads();
  u32* src = bufA;
  u32* dst = bufB;
  for (int off = 1; off < 1024; off <<= 1) {
    u32 v = src[t] + ((t + off < 1024) ? src[t + off] : 0u);
    dst[t] = v;
    __syncthreads();
    u32* tmp = src; src = dst; dst = tmp;
  }
  u32 running = src[t] - orig[t];  // items in bins above this chunk
  for (int j = 7; j >= 0; --j) {
    u32 v = hist[t * 8 + j];
    u32 nr = running + v;
    if (nr >= (u32)PRE && running < (u32)PRE) bs = t * 8 + j;  // unique crossing
    running = nr;
  }
  __syncthreads();
  if (t == 0) bstar[b] = (u32)bs;
}

// ---- K2: compact candidates — wave ballot + block aggregation (64 global atomics TOTAL) ----
__global__ __launch_bounds__(1024) void compact_kernel(const u32* __restrict__ ord,
                                                       const u32* __restrict__ bstar,
                                                       u32* __restrict__ selctr,
                                                       u64* __restrict__ candkey) {
  __shared__ u32 wbase[16];
  __shared__ u32 bbase;
  const int b = blockIdx.x >> 4;    // 16 blocks per batch
  const int blk = blockIdx.x & 15;
  const int t = threadIdx.x;
  const int n = blk * 1024 + t;     // element within batch
  u32 o = ord[(b << 14) + n];
  bool pred = (o >> 19) >= bstar[b];
  u64 mask = __ballot(pred);
  int lane = t & 63, w = t >> 6;
  if (lane == 0) wbase[w] = (u32)__popcll(mask);
  u32 lpre = (u32)__popcll(mask & ((lane == 0) ? 0ull : (~0ull >> (64 - lane))));
  __syncthreads();
  if (t == 0) {
    u32 s = 0;
#pragma unroll
    for (int i = 0; i < 16; ++i) { u32 v = wbase[i]; wbase[i] = s; s += v; }
    bbase = atomicAdd(&selctr[b], s);  // ONE global atomic per block
  }
  __syncthreads();
  if (pred) {
    u32 pos = bbase + wbase[w] + lpre;
    if (pos < SELCAP)
      candkey[(size_t)b * SELCAP + pos] = ((u64)o << 14) | (u64)(NN - 1 - n);  // score desc, idx asc
  }
}

// ---- K3: rank-by-counting (keys unique) + fused geometry gather at rank position ----
__global__ __launch_bounds__(256) void rankgeom_kernel(
    const float* __restrict__ box, const float* __restrict__ cls,
    const u32* __restrict__ selctr, const u64* __restrict__ candkey,
    u32* __restrict__ sidx, float4* __restrict__ bx4, float* __restrict__ ar,
    float* __restrict__ gsc, u32* __restrict__ glab) {
  const int blk = blockIdx.x;
  const int b = blk / (SELCAP / 256), u = blk % (SELCAP / 256);
  const int t = threadIdx.x;
  u32 C = selctr[b];
  if (C > SELCAP) C = SELCAP;
  const int cand = u * 256 + t;
  if (cand >= (int)C) return;
  const u64* __restrict__ ck = candkey + (size_t)b * SELCAP;
  const u64 mykey = ck[cand];
  u32 r = 0;
  int k = 0;
  const int C8 = (int)C & ~7;
  for (; k < C8; k += 8) {
    // k wave-uniform -> broadcast loads; 48 KB/batch stream, L1/L2-hot
    u64 k0 = ck[k], k1 = ck[k + 1], k2 = ck[k + 2], k3 = ck[k + 3];
    u64 k4 = ck[k + 4], k5 = ck[k + 5], k6 = ck[k + 6], k7 = ck[k + 7];
    r += (u32)(k0 > mykey) + (u32)(k1 > mykey) + (u32)(k2 > mykey) + (u32)(k3 > mykey);
    r += (u32)(k4 > mykey) + (u32)(k5 > mykey) + (u32)(k6 > mykey) + (u32)(k7 > mykey);
  }
  for (; k < (int)C; ++k) r += (u32)(ck[k] > mykey);
  if (r >= (u32)PRE) return;
  const int idx = (NN - 1) - (int)(mykey & 0x3FFFull);
  const int g = (b << 12) + (int)r;
  sidx[g] = (u32)idx;
  const float* bp = box + ((size_t)(b << 14) + idx) * 7;
  float x = bp[0], y = bp[1];
  float dx = bp[3], dy = bp[4];
  float4 v;
  v.x = x - dx * 0.5f;   // x1
  v.y = x + dx * 0.5f;   // x2
  v.z = y - dy * 0.5f;   // y1
  v.w = y + dy * 0.5f;   // y2
  bx4[g] = v;
  ar[g] = dx * dy;
  const float* cp = cls + ((size_t)(b << 14) + idx) * 3;
  float f0 = cp[0], f1 = cp[1], f2 = cp[2];
  int lab = 0;
  float best = f0;
  if (f1 > best) { best = f1; lab = 1; }
  if (f2 > best) { best = f2; lab = 2; }
  gsc[g] = best;
  glab[g] = (u32)lab;
}

// ---- K4: sparse suppression graph — LDS-tiled, triangular grid, 4x4 register blocking ----
__global__ __launch_bounds__(256) void pairs_kernel(const float4* __restrict__ bx4,
                                                    const float* __restrict__ ar,
                                                    u32* __restrict__ cnt,
                                                    u32* __restrict__ adj,
                                                    u64* __restrict__ hasadj) {
  __shared__ float4 si4[64], sj4[64];
  __shared__ float sia[64], sja[64];
  const int bid = blockIdx.x;
  const int b = bid / NTRI;
  const int rr = bid % NTRI;
  // decode upper-tri tile (ti<=tj) from reversed triangular index
  int m = NTRI - 1 - rr;
  int q = (int)((sqrtf(8.0f * (float)m + 1.0f) - 1.0f) * 0.5f);
  while ((q + 1) * (q + 2) / 2 <= m) ++q;
  while (q * (q + 1) / 2 > m) --q;
  int p = m - q * (q + 1) / 2;
  const int ti = 63 - q, tj = 63 - q + p;  // ti <= tj
  const int tid = threadIdx.x;
  const int base = b << 12;
  if (tid < 64) {
    si4[tid] = bx4[base + ti * 64 + tid];
    sia[tid] = ar[base + ti * 64 + tid];
  } else if (tid < 128) {
    int l = tid - 64;
    sj4[l] = bx4[base + tj * 64 + l];
    sja[l] = ar[base + tj * 64 + l];
  }
  __syncthreads();
  const int i0 = (tid & 15) * 4, j0 = (tid >> 4) * 4;
  float4 A[4], Bv[4];
  float Aa[4], Ba[4];
#pragma unroll
  for (int a = 0; a < 4; ++a) { A[a] = si4[i0 + a]; Aa[a] = sia[i0 + a]; }
#pragma unroll
  for (int c = 0; c < 4; ++c) { Bv[c] = sj4[j0 + c]; Ba[c] = sja[j0 + c]; }
#pragma unroll
  for (int a = 0; a < 4; ++a) {
#pragma unroll
    for (int c = 0; c < 4; ++c) {
      const int i = ti * 64 + i0 + a;
      const int j = tj * 64 + j0 + c;
      if (j <= i) continue;  // upper triangle within diag tile
      float ix = fminf(A[a].y, Bv[c].y) - fmaxf(A[a].x, Bv[c].x);
      ix = fmaxf(ix, 0.0f);
      float iy = fminf(A[a].w, Bv[c].w) - fmaxf(A[a].z, Bv[c].z);
      iy = fmaxf(iy, 0.0f);
      float inter = ix * iy;
      float denom = ((Aa[a] + Ba[c]) - inter) + 1e-6f;  // np op order
      float iou = inter / denom;                        // IEEE f32 div
      if (iou > 0.8f) {
        int gi = base + i;
        u32 pos = atomicAdd(&cnt[gi], 1u);
        if (pos < CAP) adj[(size_t)gi * CAP + pos] = (u32)j;
        if (pos == 0u) atomicOr(&hasadj[(b << 6) + (i >> 6)], 1ull << (i & 63));
      }
    }
  }
}

// ---- K5: sequential NMS scan (lane 0) + all outputs (f32) ----
__global__ __launch_bounds__(256) void nms_kernel(
    const float* __restrict__ box, const float* __restrict__ gt,
    const u32* __restrict__ sidx, const float* __restrict__ gsc,
    const u32* __restrict__ glab, const u32* __restrict__ cnt,
    const u32* __restrict__ adj, const u64* __restrict__ hasadj,
    float* __restrict__ out) {
  __shared__ u64 sval[64];
  __shared__ u64 shadj[64];
  __shared__ u16 ssel[POST];
  __shared__ u16 skeep[POST];
  const int b = blockIdx.x, tid = threadIdx.x;
  if (tid < 64) {
    sval[tid] = ~0ull;
    shadj[tid] = hasadj[(b << 6) + tid];
  }
  __syncthreads();
  if (tid == 0) {
    int t = 0, wi = 0;
    u64 cw = sval[0], ha = shadj[0];
    while (t < POST) {
      if (cw == 0ull) {
        ++wi;
        if (wi == 64) break;
        cw = sval[wi];
        ha = shadj[wi];
        continue;
      }
      int bit = __ffsll((unsigned long long)cw) - 1;
      cw &= cw - 1;  // consume lowest set bit (= argmax(valid))
      int i = (wi << 6) + bit;
      ssel[t] = (u16)i;
      skeep[t] = 1;
      if ((ha >> bit) & 1ull) {  // rare: this box suppresses someone
        int c = (int)cnt[(b << 12) + i];
        if (c > CAP) c = CAP;
        for (int k2 = 0; k2 < c; ++k2) {
          u32 j = adj[((size_t)((b << 12) + i)) * CAP + k2];  // all j > i
          int wj = (int)(j >> 6);
          u64 mask = ~(1ull << (j & 63u));
          if (wj == wi) cw &= mask;
          else sval[wj] &= mask;
        }
      }
      ++t;
    }
    for (; t < POST; ++t) { ssel[t] = 0; skeep[t] = 0; }
  }
  __syncthreads();

  float* rois = out;                  // B*POST*7
  float* rsc  = out + BB * POST * 7;  // B*POST
  float* rlb  = rsc + BB * POST;      // B*POST
  float* rct  = rlb + BB * POST;      // B*POST*8

  const float TWO_PI_F = 6.283185307179586f;
  const float PI_F = 3.14159265358979323846f;
  const float HALF_PI_F = 1.5707963267948966f;
  const float THREE_HALF_PI_F = 4.71238898038469f;

  for (int t = tid; t < POST; t += 256) {
    int i = ssel[t];
    int kp = skeep[t];
    int g = (b << 12) + i;
    u32 idx = sidx[g];
    const float* bp = box + ((size_t)(b << 14) + idx) * 7;
    float bx[7];
#pragma unroll
    for (int d = 0; d < 7; ++d) bx[d] = kp ? bp[d] : 0.0f;
    float* ro = rois + ((size_t)b * POST + t) * 7;
#pragma unroll
    for (int d = 0; d < 7; ++d) ro[d] = bx[d];
    rsc[b * POST + t] = kp ? gsc[g] : 0.0f;
    rlb[b * POST + t] = (float)((kp ? (int)glab[g] : 0) + 1);

    // canonical transform in f32, matching np op order
    const float* gp = gt + ((size_t)b * POST + t) * 8;
    float g0 = gp[0], g1 = gp[1], g2 = gp[2], g6 = gp[6];
    float rr = fmodf(bx[6], TWO_PI_F);
    if (rr < 0.0f) rr += TWO_PI_F;
    float xyz0 = g0 - bx[0], xyz1 = g1 - bx[1], xyz2 = g2 - bx[2];
    float heading = g6 - rr;
    float aa = -rr;
    float cc = cosf(aa), s2 = sinf(aa);
    float nx = xyz0 * cc - xyz1 * s2;
    float ny = xyz0 * s2 + xyz1 * cc;
    float h = fmodf(heading, TWO_PI_F);
    if (h < 0.0f) h += TWO_PI_F;
    bool opp = (h > HALF_PI_F) && (h < THREE_HALF_PI_F);
    if (opp) {
      h = fmodf(h + PI_F, TWO_PI_F);
      if (h < 0.0f) h += TWO_PI_F;
    }
    if (h > PI_F) h -= TWO_PI_F;
    h = fminf(fmaxf(h, -HALF_PI_F), HALF_PI_F);

    float* co = rct + ((size_t)b * POST + t) * 8;
    co[0] = nx;
    co[1] = ny;
    co[2] = xyz2;
    co[3] = gp[3];
    co[4] = gp[4];
    co[5] = gp[5];
    co[6] = h;
    co[7] = gp[7];
  }
}

extern "C" void kernel_launch(void* const* d_in, const int* in_sizes, int n_in,
                              void* d_out, int out_size, void* d_ws, size_t ws_size,
                              hipStream_t stream) {
  const float* box = (const float*)d_in[0];  // (B,N,7) f32
  const float* cls = (const float*)d_in[1];  // (B,N,3) f32
  const float* gt  = (const float*)d_in[2];  // (B,POST,8) f32
  float* out = (float*)d_out;                // 34816 f32, concat in return order

  char* ws = (char*)d_ws;
  size_t off = 0;
  auto alloc = [&](size_t bytes) -> void* {
    void* p = ws + off;
    off += (bytes + 255) & ~(size_t)255;
    return p;
  };
  u32* ord     = (u32*)alloc((size_t)BB * NN * 4);      // 256 KB
  u32* bstar   = (u32*)alloc((size_t)BB * 4);
  u32* selctr  = (u32*)alloc((size_t)BB * 4);
  u64* candkey = (u64*)alloc((size_t)BB * SELCAP * 8);  // 192 KB
  u32* sidx    = (u32*)alloc((size_t)BB * PRE * 4);
  float4* bx4  = (float4*)alloc((size_t)BB * PRE * 16);
  float* ar    = (float*)alloc((size_t)BB * PRE * 4);
  float* gsc   = (float*)alloc((size_t)BB * PRE * 4);
  u32* glab    = (u32*)alloc((size_t)BB * PRE * 4);
  u32* cnt     = (u32*)alloc((size_t)BB * PRE * 4);
  u64* hasadj  = (u64*)alloc((size_t)BB * 64 * 8);
  u32* adj     = (u32*)alloc((size_t)BB * PRE * CAP * 4);  // 2 MB

  hipLaunchKernelGGL(histbstar_kernel, dim3(BB), dim3(1024), 0, stream,
                     cls, ord, bstar, selctr, cnt, hasadj);
  hipLaunchKernelGGL(compact_kernel, dim3(BB * 16), dim3(1024), 0, stream,
                     ord, bstar, selctr, candkey);
  hipLaunchKernelGGL(rankgeom_kernel, dim3(BB * (SELCAP / 256)), dim3(256), 0, stream,
                     box, cls, selctr, candkey, sidx, bx4, ar, gsc, glab);
  hipLaunchKernelGGL(pairs_kernel, dim3(BB * NTRI), dim3(256), 0, stream,
                     bx4, ar, cnt, adj, hasadj);
  hipLaunchKernelGGL(nms_kernel, dim3(BB), dim3(256), 0, stream,
                     box, gt, sidx, gsc, glab, cnt, adj, hasadj, out);
}

// Round 6
// 165.624 us; speedup vs baseline: 3.1974x; 1.8058x over previous
//
#include <hip/hip_runtime.h>
#include <cstdint>
#include <cstddef>

#define BB 4
#define NN 16384
#define PRE 4096
#define POST 512
#define CAP 32
#define SELCAP 6144   // C = 4096 + one 13-bit bin (~500) << 6144
#define BINS 8192     // top-13 bits of f32 ordinal
#define NTRI 2080     // 64*65/2 upper-tri tiles for pairs
#define RTILE 1024    // candidates per rank block (256 thr x 4)
#define RCHUNK 512    // keys per rank block chunk
#define NTC (SELCAP / RTILE)   // 6
#define NCH (SELCAP / RCHUNK)  // 12

typedef unsigned short u16;
typedef unsigned int u32;
typedef unsigned long long u64;

// monotone map: f32 bits -> u32 ordinal preserving float order
__device__ __forceinline__ u32 ord32(float f) {
  u32 u = __builtin_bit_cast(u32, f);
  return (u & 0x80000000u) ? ~u : (u | 0x80000000u);
}

// ---- K1: score->ord, LDS histogram, threshold bin B*; zero selctr/cnt/hasadj/rank ----
__global__ __launch_bounds__(1024) void histbstar_kernel(const float* __restrict__ cls,
                                                         u32* __restrict__ ord,
                                                         u32* __restrict__ bstar,
                                                         u32* __restrict__ selctr,
                                                         u32* __restrict__ cnt,
                                                         u64* __restrict__ hasadj,
                                                         u32* __restrict__ rank) {
  __shared__ u32 hist[BINS];   // 32 KB
  __shared__ u32 orig[1024];
  __shared__ u32 bufA[1024];
  __shared__ u32 bufB[1024];   // +12 KB
  __shared__ int bs;
  const int b = blockIdx.x, t = threadIdx.x;
  for (int p = t; p < BINS; p += 1024) hist[p] = 0u;
  if (t == 0) { bs = 0; selctr[b] = 0u; }
  if (t < 64) hasadj[(b << 6) + t] = 0ull;
  for (int p = t; p < PRE; p += 1024) cnt[(b << 12) + p] = 0u;
  for (int p = t; p < SELCAP; p += 1024) rank[b * SELCAP + p] = 0u;
  __syncthreads();
  const float* c = cls + (size_t)b * NN * 3;
  for (int n = t; n < NN; n += 1024) {
    float s = fmaxf(fmaxf(c[n * 3], c[n * 3 + 1]), c[n * 3 + 2]);
    u32 o = ord32(s);
    ord[b * NN + n] = o;
    atomicAdd(&hist[o >> 19], 1u);
  }
  __syncthreads();
  u32 s = 0;
#pragma unroll
  for (int j = 0; j < 8; ++j) s += hist[t * 8 + j];
  orig[t] = s;
  bufA[t] = s;
  __syncthreads();
  u32* src = bufA;
  u32* dst = bufB;
  for (int off = 1; off < 1024; off <<= 1) {
    u32 v = src[t] + ((t + off < 1024) ? src[t + off] : 0u);
    dst[t] = v;
    __syncthreads();
    u32* tmp = src; src = dst; dst = tmp;
  }
  u32 running = src[t] - orig[t];  // items in bins above this chunk
  for (int j = 7; j >= 0; --j) {
    u32 v = hist[t * 8 + j];
    u32 nr = running + v;
    if (nr >= (u32)PRE && running < (u32)PRE) bs = t * 8 + j;  // unique crossing
    running = nr;
  }
  __syncthreads();
  if (t == 0) bstar[b] = (u32)bs;
}

// ---- K2: compact candidates — wave ballot + block aggregation ----
__global__ __launch_bounds__(1024) void compact_kernel(const u32* __restrict__ ord,
                                                       const u32* __restrict__ bstar,
                                                       u32* __restrict__ selctr,
                                                       u64* __restrict__ candkey) {
  __shared__ u32 wbase[16];
  __shared__ u32 bbase;
  const int b = blockIdx.x >> 4;    // 16 blocks per batch
  const int blk = blockIdx.x & 15;
  const int t = threadIdx.x;
  const int n = blk * 1024 + t;     // element within batch
  u32 o = ord[(b << 14) + n];
  bool pred = (o >> 19) >= bstar[b];
  u64 mask = __ballot(pred);
  int lane = t & 63, w = t >> 6;
  if (lane == 0) wbase[w] = (u32)__popcll(mask);
  u32 lpre = (u32)__popcll(mask & ((lane == 0) ? 0ull : (~0ull >> (64 - lane))));
  __syncthreads();
  if (t == 0) {
    u32 s = 0;
#pragma unroll
    for (int i = 0; i < 16; ++i) { u32 v = wbase[i]; wbase[i] = s; s += v; }
    bbase = atomicAdd(&selctr[b], s);  // ONE global atomic per block
  }
  __syncthreads();
  if (pred) {
    u32 pos = bbase + wbase[w] + lpre;
    if (pos < SELCAP)
      candkey[(size_t)b * SELCAP + pos] = ((u64)o << 14) | (u64)(NN - 1 - n);  // score desc, idx asc
  }
}

// ---- K3a: partial rank-by-counting, key-chunk split, LDS-staged ----
__global__ __launch_bounds__(256) void rank_kernel(const u32* __restrict__ selctr,
                                                   const u64* __restrict__ candkey,
                                                   u32* __restrict__ rank) {
  __shared__ u64 sk[RCHUNK];  // 4 KB
  const int bid = blockIdx.x;
  const int b = bid / (NTC * NCH);
  const int rem = bid % (NTC * NCH);
  const int ct = rem / NCH, kc = rem % NCH;
  u32 C = selctr[b];
  if (C > SELCAP) C = SELCAP;
  const int kbase = kc * RCHUNK;
  const int cbase = ct * RTILE;
  if ((u32)kbase >= C || (u32)cbase >= C) return;
  const u64* __restrict__ ck = candkey + (size_t)b * SELCAP;
  const int t = threadIdx.x;
  for (int s = t; s < RCHUNK; s += 256) {
    int slot = kbase + s;
    sk[s] = (slot < (int)C) ? ck[slot] : 0ull;  // 0 < any real key
  }
  __syncthreads();
  u64 my[4];
  u32 r[4] = {0u, 0u, 0u, 0u};
#pragma unroll
  for (int a = 0; a < 4; ++a) {
    int cand = cbase + a * 256 + t;
    my[a] = (cand < (int)C) ? ck[cand] : ~0ull;  // ~0: nothing greater
  }
  const int kn = min((int)C - kbase, RCHUNK);
  int k = 0;
  for (; k + 4 <= kn; k += 4) {
    u64 k0 = sk[k], k1 = sk[k + 1], k2 = sk[k + 2], k3 = sk[k + 3];
#pragma unroll
    for (int a = 0; a < 4; ++a)
      r[a] += (u32)(k0 > my[a]) + (u32)(k1 > my[a]) + (u32)(k2 > my[a]) + (u32)(k3 > my[a]);
  }
  for (; k < kn; ++k) {
    u64 kv = sk[k];
#pragma unroll
    for (int a = 0; a < 4; ++a) r[a] += (u32)(kv > my[a]);
  }
#pragma unroll
  for (int a = 0; a < 4; ++a) {
    int cand = cbase + a * 256 + t;
    if (cand < (int)C && r[a] > 0u)
      atomicAdd(&rank[(size_t)b * SELCAP + cand], r[a]);
  }
}

// ---- K3b: scatter by final rank + fused geometry gather ----
__global__ __launch_bounds__(256) void scatter_kernel(
    const float* __restrict__ box, const float* __restrict__ cls,
    const u32* __restrict__ selctr, const u64* __restrict__ candkey,
    const u32* __restrict__ rank,
    u32* __restrict__ sidx, float4* __restrict__ bx4, float* __restrict__ ar,
    float* __restrict__ gsc, u32* __restrict__ glab) {
  const int gg = blockIdx.x * 256 + threadIdx.x;
  if (gg >= BB * SELCAP) return;
  const int b = gg / SELCAP, cand = gg % SELCAP;
  u32 C = selctr[b];
  if (C > SELCAP) C = SELCAP;
  if (cand >= (int)C) return;
  const u32 r = rank[gg];
  if (r >= (u32)PRE) return;
  const u64 mykey = candkey[(size_t)b * SELCAP + cand];
  const int idx = (NN - 1) - (int)(mykey & 0x3FFFull);
  const int g = (b << 12) + (int)r;
  sidx[g] = (u32)idx;
  const float* bp = box + ((size_t)(b << 14) + idx) * 7;
  float x = bp[0], y = bp[1];
  float dx = bp[3], dy = bp[4];
  float4 v;
  v.x = x - dx * 0.5f;   // x1
  v.y = x + dx * 0.5f;   // x2
  v.z = y - dy * 0.5f;   // y1
  v.w = y + dy * 0.5f;   // y2
  bx4[g] = v;
  ar[g] = dx * dy;
  const float* cp = cls + ((size_t)(b << 14) + idx) * 3;
  float f0 = cp[0], f1 = cp[1], f2 = cp[2];
  int lab = 0;
  float best = f0;
  if (f1 > best) { best = f1; lab = 1; }
  if (f2 > best) { best = f2; lab = 2; }
  gsc[g] = best;
  glab[g] = (u32)lab;
}

// ---- K4: sparse suppression graph — LDS-tiled, triangular grid, 4x4 register blocking ----
__global__ __launch_bounds__(256) void pairs_kernel(const float4* __restrict__ bx4,
                                                    const float* __restrict__ ar,
                                                    u32* __restrict__ cnt,
                                                    u32* __restrict__ adj,
                                                    u64* __restrict__ hasadj) {
  __shared__ float4 si4[64], sj4[64];
  __shared__ float sia[64], sja[64];
  const int bid = blockIdx.x;
  const int b = bid / NTRI;
  const int rr = bid % NTRI;
  // decode upper-tri tile (ti<=tj) from reversed triangular index
  int m = NTRI - 1 - rr;
  int q = (int)((sqrtf(8.0f * (float)m + 1.0f) - 1.0f) * 0.5f);
  while ((q + 1) * (q + 2) / 2 <= m) ++q;
  while (q * (q + 1) / 2 > m) --q;
  int p = m - q * (q + 1) / 2;
  const int ti = 63 - q, tj = 63 - q + p;  // ti <= tj
  const int tid = threadIdx.x;
  const int base = b << 12;
  if (tid < 64) {
    si4[tid] = bx4[base + ti * 64 + tid];
    sia[tid] = ar[base + ti * 64 + tid];
  } else if (tid < 128) {
    int l = tid - 64;
    sj4[l] = bx4[base + tj * 64 + l];
    sja[l] = ar[base + tj * 64 + l];
  }
  __syncthreads();
  const int i0 = (tid & 15) * 4, j0 = (tid >> 4) * 4;
  float4 A[4], Bv[4];
  float Aa[4], Ba[4];
#pragma unroll
  for (int a = 0; a < 4; ++a) { A[a] = si4[i0 + a]; Aa[a] = sia[i0 + a]; }
#pragma unroll
  for (int c = 0; c < 4; ++c) { Bv[c] = sj4[j0 + c]; Ba[c] = sja[j0 + c]; }
#pragma unroll
  for (int a = 0; a < 4; ++a) {
#pragma unroll
    for (int c = 0; c < 4; ++c) {
      const int i = ti * 64 + i0 + a;
      const int j = tj * 64 + j0 + c;
      if (j <= i) continue;  // upper triangle within diag tile
      float ix = fminf(A[a].y, Bv[c].y) - fmaxf(A[a].x, Bv[c].x);
      ix = fmaxf(ix, 0.0f);
      float iy = fminf(A[a].w, Bv[c].w) - fmaxf(A[a].z, Bv[c].z);
      iy = fmaxf(iy, 0.0f);
      float inter = ix * iy;
      float denom = ((Aa[a] + Ba[c]) - inter) + 1e-6f;  // np op order
      float iou = inter / denom;                        // IEEE f32 div
      if (iou > 0.8f) {
        int gi = base + i;
        u32 pos = atomicAdd(&cnt[gi], 1u);
        if (pos < CAP) adj[(size_t)gi * CAP + pos] = (u32)j;
        if (pos == 0u) atomicOr(&hasadj[(b << 6) + (i >> 6)], 1ull << (i & 63));
      }
    }
  }
}

// ---- K5: sequential NMS scan (lane 0) + all outputs (f32) ----
__global__ __launch_bounds__(256) void nms_kernel(
    const float* __restrict__ box, const float* __restrict__ gt,
    const u32* __restrict__ sidx, const float* __restrict__ gsc,
    const u32* __restrict__ glab, const u32* __restrict__ cnt,
    const u32* __restrict__ adj, const u64* __restrict__ hasadj,
    float* __restrict__ out) {
  __shared__ u64 sval[64];
  __shared__ u64 shadj[64];
  __shared__ u16 ssel[POST];
  __shared__ u16 skeep[POST];
  const int b = blockIdx.x, tid = threadIdx.x;
  if (tid < 64) {
    sval[tid] = ~0ull;
    shadj[tid] = hasadj[(b << 6) + tid];
  }
  __syncthreads();
  if (tid == 0) {
    int t = 0, wi = 0;
    u64 cw = sval[0], ha = shadj[0];
    while (t < POST) {
      if (cw == 0ull) {
        ++wi;
        if (wi == 64) break;
        cw = sval[wi];
        ha = shadj[wi];
        continue;
      }
      int bit = __ffsll((unsigned long long)cw) - 1;
      cw &= cw - 1;  // consume lowest set bit (= argmax(valid))
      int i = (wi << 6) + bit;
      ssel[t] = (u16)i;
      skeep[t] = 1;
      if ((ha >> bit) & 1ull) {  // rare: this box suppresses someone
        int c = (int)cnt[(b << 12) + i];
        if (c > CAP) c = CAP;
        for (int k2 = 0; k2 < c; ++k2) {
          u32 j = adj[((size_t)((b << 12) + i)) * CAP + k2];  // all j > i
          int wj = (int)(j >> 6);
          u64 mask = ~(1ull << (j & 63u));
          if (wj == wi) cw &= mask;
          else sval[wj] &= mask;
        }
      }
      ++t;
    }
    for (; t < POST; ++t) { ssel[t] = 0; skeep[t] = 0; }
  }
  __syncthreads();

  float* rois = out;                  // B*POST*7
  float* rsc  = out + BB * POST * 7;  // B*POST
  float* rlb  = rsc + BB * POST;      // B*POST
  float* rct  = rlb + BB * POST;      // B*POST*8

  const float TWO_PI_F = 6.283185307179586f;
  const float PI_F = 3.14159265358979323846f;
  const float HALF_PI_F = 1.5707963267948966f;
  const float THREE_HALF_PI_F = 4.71238898038469f;

  for (int t = tid; t < POST; t += 256) {
    int i = ssel[t];
    int kp = skeep[t];
    int g = (b << 12) + i;
    u32 idx = sidx[g];
    const float* bp = box + ((size_t)(b << 14) + idx) * 7;
    float bx[7];
#pragma unroll
    for (int d = 0; d < 7; ++d) bx[d] = kp ? bp[d] : 0.0f;
    float* ro = rois + ((size_t)b * POST + t) * 7;
#pragma unroll
    for (int d = 0; d < 7; ++d) ro[d] = bx[d];
    rsc[b * POST + t] = kp ? gsc[g] : 0.0f;
    rlb[b * POST + t] = (float)((kp ? (int)glab[g] : 0) + 1);

    // canonical transform in f32, matching np op order
    const float* gp = gt + ((size_t)b * POST + t) * 8;
    float g0 = gp[0], g1 = gp[1], g2 = gp[2], g6 = gp[6];
    float rr = fmodf(bx[6], TWO_PI_F);
    if (rr < 0.0f) rr += TWO_PI_F;
    float xyz0 = g0 - bx[0], xyz1 = g1 - bx[1], xyz2 = g2 - bx[2];
    float heading = g6 - rr;
    float aa = -rr;
    float cc = cosf(aa), s2 = sinf(aa);
    float nx = xyz0 * cc - xyz1 * s2;
    float ny = xyz0 * s2 + xyz1 * cc;
    float h = fmodf(heading, TWO_PI_F);
    if (h < 0.0f) h += TWO_PI_F;
    bool opp = (h > HALF_PI_F) && (h < THREE_HALF_PI_F);
    if (opp) {
      h = fmodf(h + PI_F, TWO_PI_F);
      if (h < 0.0f) h += TWO_PI_F;
    }
    if (h > PI_F) h -= TWO_PI_F;
    h = fminf(fmaxf(h, -HALF_PI_F), HALF_PI_F);

    float* co = rct + ((size_t)b * POST + t) * 8;
    co[0] = nx;
    co[1] = ny;
    co[2] = xyz2;
    co[3] = gp[3];
    co[4] = gp[4];
    co[5] = gp[5];
    co[6] = h;
    co[7] = gp[7];
  }
}

extern "C" void kernel_launch(void* const* d_in, const int* in_sizes, int n_in,
                              void* d_out, int out_size, void* d_ws, size_t ws_size,
                              hipStream_t stream) {
  const float* box = (const float*)d_in[0];  // (B,N,7) f32
  const float* cls = (const float*)d_in[1];  // (B,N,3) f32
  const float* gt  = (const float*)d_in[2];  // (B,POST,8) f32
  float* out = (float*)d_out;                // 34816 f32, concat in return order

  char* ws = (char*)d_ws;
  size_t off = 0;
  auto alloc = [&](size_t bytes) -> void* {
    void* p = ws + off;
    off += (bytes + 255) & ~(size_t)255;
    return p;
  };
  u32* ord     = (u32*)alloc((size_t)BB * NN * 4);      // 256 KB
  u32* bstar   = (u32*)alloc((size_t)BB * 4);
  u32* selctr  = (u32*)alloc((size_t)BB * 4);
  u64* candkey = (u64*)alloc((size_t)BB * SELCAP * 8);  // 192 KB
  u32* rank    = (u32*)alloc((size_t)BB * SELCAP * 4);  // 96 KB
  u32* sidx    = (u32*)alloc((size_t)BB * PRE * 4);
  float4* bx4  = (float4*)alloc((size_t)BB * PRE * 16);
  float* ar    = (float*)alloc((size_t)BB * PRE * 4);
  float* gsc   = (float*)alloc((size_t)BB * PRE * 4);
  u32* glab    = (u32*)alloc((size_t)BB * PRE * 4);
  u32* cnt     = (u32*)alloc((size_t)BB * PRE * 4);
  u64* hasadj  = (u64*)alloc((size_t)BB * 64 * 8);
  u32* adj     = (u32*)alloc((size_t)BB * PRE * CAP * 4);  // 2 MB

  hipLaunchKernelGGL(histbstar_kernel, dim3(BB), dim3(1024), 0, stream,
                     cls, ord, bstar, selctr, cnt, hasadj, rank);
  hipLaunchKernelGGL(compact_kernel, dim3(BB * 16), dim3(1024), 0, stream,
                     ord, bstar, selctr, candkey);
  hipLaunchKernelGGL(rank_kernel, dim3(BB * NTC * NCH), dim3(256), 0, stream,
                     selctr, candkey, rank);
  hipLaunchKernelGGL(scatter_kernel, dim3(BB * SELCAP / 256), dim3(256), 0, stream,
                     box, cls, selctr, candkey, rank, sidx, bx4, ar, gsc, glab);
  hipLaunchKernelGGL(pairs_kernel, dim3(BB * NTRI), dim3(256), 0, stream,
                     bx4, ar, cnt, adj, hasadj);
  hipLaunchKernelGGL(nms_kernel, dim3(BB), dim3(256), 0, stream,
                     box, gt, sidx, gsc, glab, cnt, adj, hasadj, out);
}

// Round 7
// 150.686 us; speedup vs baseline: 3.5143x; 1.0991x over previous
//
#include <hip/hip_runtime.h>
#include <cstdint>
#include <cstddef>

#define BB 4
#define NN 16384
#define PRE 4096
#define POST 512
#define SELCAP 6144   // C = 4096 + one 13-bit bin (~500) << 6144
#define BINS 8192     // top-13 bits of f32 ordinal
#define NTRI 2080     // 64*65/2 upper-tri tiles for pairs
#define RTILE 1024    // candidates per rank block (256 thr x 4)
#define RCHUNK 512    // keys per rank block chunk
#define NTC (SELCAP / RTILE)   // 6
#define NCH (SELCAP / RCHUNK)  // 12
#define ECAP 2048     // per-batch edge cap (expected E ~ tens)

typedef unsigned short u16;
typedef unsigned int u32;
typedef unsigned long long u64;

// monotone map: f32 bits -> u32 ordinal preserving float order
__device__ __forceinline__ u32 ord32(float f) {
  u32 u = __builtin_bit_cast(u32, f);
  return (u & 0x80000000u) ? ~u : (u | 0x80000000u);
}

// ---- K1: score -> ordinal + global-atomic histogram (64 blocks, full chip) ----
__global__ __launch_bounds__(1024) void hist_kernel(const float* __restrict__ cls,
                                                    u32* __restrict__ ord,
                                                    u32* __restrict__ hist) {
  const int g = blockIdx.x * 1024 + threadIdx.x;  // [0, BB*NN)
  const int b = g >> 14;
  const float* c = cls + (size_t)g * 3;
  float s = fmaxf(fmaxf(c[0], c[1]), c[2]);
  u32 o = ord32(s);
  ord[g] = o;
  atomicAdd(&hist[(b << 13) + (o >> 19)], 1u);
}

// ---- K2: threshold bin B* (rank-PRE crossing, descending) ----
__global__ __launch_bounds__(1024) void bstar_kernel(const u32* __restrict__ hist,
                                                     u32* __restrict__ bstar) {
  __shared__ u32 orig[1024];
  __shared__ u32 bufA[1024];
  __shared__ u32 bufB[1024];
  __shared__ int bs;
  const int b = blockIdx.x, t = threadIdx.x;
  const u32* h = hist + (b << 13);
  u32 s = 0;
#pragma unroll
  for (int j = 0; j < 8; ++j) s += h[t * 8 + j];
  orig[t] = s;
  bufA[t] = s;
  if (t == 0) bs = 0;
  __syncthreads();
  u32* src = bufA;
  u32* dst = bufB;
  for (int off = 1; off < 1024; off <<= 1) {
    u32 v = src[t] + ((t + off < 1024) ? src[t + off] : 0u);
    dst[t] = v;
    __syncthreads();
    u32* tmp = src; src = dst; dst = tmp;
  }
  u32 running = src[t] - orig[t];  // items in bins above this chunk
  for (int j = 7; j >= 0; --j) {
    u32 v = h[t * 8 + j];
    u32 nr = running + v;
    if (nr >= (u32)PRE && running < (u32)PRE) bs = t * 8 + j;  // unique crossing
    running = nr;
  }
  __syncthreads();
  if (t == 0) bstar[b] = (u32)bs;
}

// ---- K3: compact candidates — wave ballot + block aggregation ----
__global__ __launch_bounds__(1024) void compact_kernel(const u32* __restrict__ ord,
                                                       const u32* __restrict__ bstar,
                                                       u32* __restrict__ selctr,
                                                       u64* __restrict__ candkey) {
  __shared__ u32 wbase[16];
  __shared__ u32 bbase;
  const int b = blockIdx.x >> 4;    // 16 blocks per batch
  const int blk = blockIdx.x & 15;
  const int t = threadIdx.x;
  const int n = blk * 1024 + t;     // element within batch
  u32 o = ord[(b << 14) + n];
  bool pred = (o >> 19) >= bstar[b];
  u64 mask = __ballot(pred);
  int lane = t & 63, w = t >> 6;
  if (lane == 0) wbase[w] = (u32)__popcll(mask);
  u32 lpre = (u32)__popcll(mask & ((lane == 0) ? 0ull : (~0ull >> (64 - lane))));
  __syncthreads();
  if (t == 0) {
    u32 s = 0;
#pragma unroll
    for (int i = 0; i < 16; ++i) { u32 v = wbase[i]; wbase[i] = s; s += v; }
    bbase = atomicAdd(&selctr[b], s);  // ONE global atomic per block
  }
  __syncthreads();
  if (pred) {
    u32 pos = bbase + wbase[w] + lpre;
    if (pos < SELCAP)
      candkey[(size_t)b * SELCAP + pos] = ((u64)o << 14) | (u64)(NN - 1 - n);  // score desc, idx asc
  }
}

// ---- K4: partial rank-by-counting, key-chunk split, LDS-staged ----
__global__ __launch_bounds__(256) void rank_kernel(const u32* __restrict__ selctr,
                                                   const u64* __restrict__ candkey,
                                                   u32* __restrict__ rank) {
  __shared__ u64 sk[RCHUNK];  // 4 KB
  const int bid = blockIdx.x;
  const int b = bid / (NTC * NCH);
  const int rem = bid % (NTC * NCH);
  const int ct = rem / NCH, kc = rem % NCH;
  u32 C = selctr[b];
  if (C > SELCAP) C = SELCAP;
  const int kbase = kc * RCHUNK;
  const int cbase = ct * RTILE;
  if ((u32)kbase >= C || (u32)cbase >= C) return;
  const u64* __restrict__ ck = candkey + (size_t)b * SELCAP;
  const int t = threadIdx.x;
  for (int s = t; s < RCHUNK; s += 256) {
    int slot = kbase + s;
    sk[s] = (slot < (int)C) ? ck[slot] : 0ull;  // 0 < any real key
  }
  __syncthreads();
  u64 my[4];
  u32 r[4] = {0u, 0u, 0u, 0u};
#pragma unroll
  for (int a = 0; a < 4; ++a) {
    int cand = cbase + a * 256 + t;
    my[a] = (cand < (int)C) ? ck[cand] : ~0ull;  // ~0: nothing greater
  }
  const int kn = min((int)C - kbase, RCHUNK);
  int k = 0;
  for (; k + 4 <= kn; k += 4) {
    u64 k0 = sk[k], k1 = sk[k + 1], k2 = sk[k + 2], k3 = sk[k + 3];
#pragma unroll
    for (int a = 0; a < 4; ++a)
      r[a] += (u32)(k0 > my[a]) + (u32)(k1 > my[a]) + (u32)(k2 > my[a]) + (u32)(k3 > my[a]);
  }
  for (; k < kn; ++k) {
    u64 kv = sk[k];
#pragma unroll
    for (int a = 0; a < 4; ++a) r[a] += (u32)(kv > my[a]);
  }
#pragma unroll
  for (int a = 0; a < 4; ++a) {
    int cand = cbase + a * 256 + t;
    if (cand < (int)C && r[a] > 0u)
      atomicAdd(&rank[(size_t)b * SELCAP + cand], r[a]);
  }
}

// ---- K5: scatter by final rank + fused geometry gather ----
__global__ __launch_bounds__(256) void scatter_kernel(
    const float* __restrict__ box, const float* __restrict__ cls,
    const u32* __restrict__ selctr, const u64* __restrict__ candkey,
    const u32* __restrict__ rank,
    u32* __restrict__ sidx, float4* __restrict__ bx4, float* __restrict__ ar,
    float* __restrict__ gsc, u32* __restrict__ glab) {
  const int gg = blockIdx.x * 256 + threadIdx.x;
  if (gg >= BB * SELCAP) return;
  const int b = gg / SELCAP, cand = gg % SELCAP;
  u32 C = selctr[b];
  if (C > SELCAP) C = SELCAP;
  if (cand >= (int)C) return;
  const u32 r = rank[gg];
  if (r >= (u32)PRE) return;
  const u64 mykey = candkey[(size_t)b * SELCAP + cand];
  const int idx = (NN - 1) - (int)(mykey & 0x3FFFull);
  const int g = (b << 12) + (int)r;
  sidx[g] = (u32)idx;
  const float* bp = box + ((size_t)(b << 14) + idx) * 7;
  float x = bp[0], y = bp[1];
  float dx = bp[3], dy = bp[4];
  float4 v;
  v.x = x - dx * 0.5f;   // x1
  v.y = x + dx * 0.5f;   // x2
  v.z = y - dy * 0.5f;   // y1
  v.w = y + dy * 0.5f;   // y2
  bx4[g] = v;
  ar[g] = dx * dy;
  const float* cp = cls + ((size_t)(b << 14) + idx) * 3;
  float f0 = cp[0], f1 = cp[1], f2 = cp[2];
  int lab = 0;
  float best = f0;
  if (f1 > best) { best = f1; lab = 1; }
  if (f2 > best) { best = f2; lab = 2; }
  gsc[g] = best;
  glab[g] = (u32)lab;
}

// ---- K6: sparse edges (i<j, IoU>0.8) -> compact per-batch edge list ----
__global__ __launch_bounds__(256) void pairs_kernel(const float4* __restrict__ bx4,
                                                    const float* __restrict__ ar,
                                                    u32* __restrict__ edgecnt,
                                                    u32* __restrict__ edges) {
  __shared__ float4 si4[64], sj4[64];
  __shared__ float sia[64], sja[64];
  const int bid = blockIdx.x;
  const int b = bid / NTRI;
  const int rr = bid % NTRI;
  // decode upper-tri tile (ti<=tj) from reversed triangular index
  int m = NTRI - 1 - rr;
  int q = (int)((sqrtf(8.0f * (float)m + 1.0f) - 1.0f) * 0.5f);
  while ((q + 1) * (q + 2) / 2 <= m) ++q;
  while (q * (q + 1) / 2 > m) --q;
  int p = m - q * (q + 1) / 2;
  const int ti = 63 - q, tj = 63 - q + p;  // ti <= tj
  const int tid = threadIdx.x;
  const int base = b << 12;
  if (tid < 64) {
    si4[tid] = bx4[base + ti * 64 + tid];
    sia[tid] = ar[base + ti * 64 + tid];
  } else if (tid < 128) {
    int l = tid - 64;
    sj4[l] = bx4[base + tj * 64 + l];
    sja[l] = ar[base + tj * 64 + l];
  }
  __syncthreads();
  const int i0 = (tid & 15) * 4, j0 = (tid >> 4) * 4;
  float4 A[4], Bv[4];
  float Aa[4], Ba[4];
#pragma unroll
  for (int a = 0; a < 4; ++a) { A[a] = si4[i0 + a]; Aa[a] = sia[i0 + a]; }
#pragma unroll
  for (int c = 0; c < 4; ++c) { Bv[c] = sj4[j0 + c]; Ba[c] = sja[j0 + c]; }
#pragma unroll
  for (int a = 0; a < 4; ++a) {
#pragma unroll
    for (int c = 0; c < 4; ++c) {
      const int i = ti * 64 + i0 + a;
      const int j = tj * 64 + j0 + c;
      if (j <= i) continue;  // upper triangle within diag tile
      float ix = fminf(A[a].y, Bv[c].y) - fmaxf(A[a].x, Bv[c].x);
      ix = fmaxf(ix, 0.0f);
      float iy = fminf(A[a].w, Bv[c].w) - fmaxf(A[a].z, Bv[c].z);
      iy = fmaxf(iy, 0.0f);
      float inter = ix * iy;
      float denom = ((Aa[a] + Ba[c]) - inter) + 1e-6f;  // np op order
      float iou = inter / denom;                        // IEEE f32 div
      if (iou > 0.8f) {                                 // rare (~tens per batch)
        u32 pos = atomicAdd(&edgecnt[b], 1u);
        if (pos < ECAP) edges[(b << 11) + pos] = ((u32)i << 12) | (u32)j;
      }
    }
  }
}

// ---- K7: edge-driven NMS resolution (E iters, not 512) + all outputs (f32) ----
__global__ __launch_bounds__(256) void nms_kernel(
    const float* __restrict__ box, const float* __restrict__ gt,
    const u32* __restrict__ sidx, const float* __restrict__ gsc,
    const u32* __restrict__ glab, const u32* __restrict__ edgecnt,
    const u32* __restrict__ edges, float* __restrict__ out) {
  __shared__ u32 sedge[ECAP];   // 8 KB
  __shared__ u32 ssort[ECAP];   // 8 KB
  __shared__ u64 ssup[64];
  __shared__ u32 spop[65];
  __shared__ u16 ssel[POST];
  __shared__ u16 skeep[POST];
  const int b = blockIdx.x, tid = threadIdx.x;
  int E = (int)edgecnt[b];
  if (E > ECAP) E = ECAP;
  if (tid < 64) ssup[tid] = 0ull;
  for (int e = tid; e < E; e += 256) sedge[e] = edges[(b << 11) + e];
  for (int t2 = tid; t2 < POST; t2 += 256) ssel[t2] = 0;
  __syncthreads();
  // sort edges ascending by (i<<12|j) — unique keys, rank-by-count
  for (int e = tid; e < E; e += 256) {
    u32 key = sedge[e];
    u32 r = 0;
    for (int k = 0; k < E; ++k) r += (u32)(sedge[k] < key);
    ssort[r] = key;
  }
  __syncthreads();
  // forward resolution in source-index order (equiv. to untruncated greedy scan)
  if (tid == 0) {
    for (int e = 0; e < E; ++e) {
      u32 v = ssort[e];
      u32 i = v >> 12, j = v & 4095u;
      if (!((ssup[i >> 6] >> (i & 63u)) & 1ull)) ssup[j >> 6] |= (1ull << (j & 63u));
    }
  }
  __syncthreads();
  if (tid < 64) spop[tid] = (u32)__popcll(~ssup[tid]);
  __syncthreads();
  if (tid == 0) {
    u32 acc = 0;
    for (int w = 0; w < 64; ++w) { u32 v = spop[w]; spop[w] = acc; acc += v; }
    spop[64] = acc;
  }
  __syncthreads();
  const int ns = (int)spop[64];
  if (tid < 64) {
    u64 w = ~ssup[tid];
    u32 base2 = spop[tid];
    while (w) {
      int bit = __ffsll((unsigned long long)w) - 1;
      w &= w - 1;
      if (base2 >= (u32)POST) break;
      ssel[base2] = (u16)((tid << 6) + bit);
      ++base2;
    }
  }
  for (int t2 = tid; t2 < POST; t2 += 256) skeep[t2] = (t2 < ns) ? (u16)1 : (u16)0;
  __syncthreads();

  float* rois = out;                  // B*POST*7
  float* rsc  = out + BB * POST * 7;  // B*POST
  float* rlb  = rsc + BB * POST;      // B*POST
  float* rct  = rlb + BB * POST;      // B*POST*8

  const float TWO_PI_F = 6.283185307179586f;
  const float PI_F = 3.14159265358979323846f;
  const float HALF_PI_F = 1.5707963267948966f;
  const float THREE_HALF_PI_F = 4.71238898038469f;

  for (int t = tid; t < POST; t += 256) {
    int i = ssel[t];
    int kp = skeep[t];
    int g = (b << 12) + i;
    u32 idx = sidx[g];
    const float* bp = box + ((size_t)(b << 14) + idx) * 7;
    float bx[7];
#pragma unroll
    for (int d = 0; d < 7; ++d) bx[d] = kp ? bp[d] : 0.0f;
    float* ro = rois + ((size_t)b * POST + t) * 7;
#pragma unroll
    for (int d = 0; d < 7; ++d) ro[d] = bx[d];
    rsc[b * POST + t] = kp ? gsc[g] : 0.0f;
    rlb[b * POST + t] = (float)((kp ? (int)glab[g] : 0) + 1);

    // canonical transform in f32, matching np op order
    const float* gp = gt + ((size_t)b * POST + t) * 8;
    float g0 = gp[0], g1 = gp[1], g2 = gp[2], g6 = gp[6];
    float rr = fmodf(bx[6], TWO_PI_F);
    if (rr < 0.0f) rr += TWO_PI_F;
    float xyz0 = g0 - bx[0], xyz1 = g1 - bx[1], xyz2 = g2 - bx[2];
    float heading = g6 - rr;
    float aa = -rr;
    float cc = cosf(aa), s2 = sinf(aa);
    float nx = xyz0 * cc - xyz1 * s2;
    float ny = xyz0 * s2 + xyz1 * cc;
    float h = fmodf(heading, TWO_PI_F);
    if (h < 0.0f) h += TWO_PI_F;
    bool opp = (h > HALF_PI_F) && (h < THREE_HALF_PI_F);
    if (opp) {
      h = fmodf(h + PI_F, TWO_PI_F);
      if (h < 0.0f) h += TWO_PI_F;
    }
    if (h > PI_F) h -= TWO_PI_F;
    h = fminf(fmaxf(h, -HALF_PI_F), HALF_PI_F);

    float* co = rct + ((size_t)b * POST + t) * 8;
    co[0] = nx;
    co[1] = ny;
    co[2] = xyz2;
    co[3] = gp[3];
    co[4] = gp[4];
    co[5] = gp[5];
    co[6] = h;
    co[7] = gp[7];
  }
}

extern "C" void kernel_launch(void* const* d_in, const int* in_sizes, int n_in,
                              void* d_out, int out_size, void* d_ws, size_t ws_size,
                              hipStream_t stream) {
  const float* box = (const float*)d_in[0];  // (B,N,7) f32
  const float* cls = (const float*)d_in[1];  // (B,N,3) f32
  const float* gt  = (const float*)d_in[2];  // (B,POST,8) f32
  float* out = (float*)d_out;                // 34816 f32, concat in return order

  char* ws = (char*)d_ws;
  size_t off = 0;
  auto alloc = [&](size_t bytes) -> void* {
    void* p = ws + off;
    off += (bytes + 255) & ~(size_t)255;
    return p;
  };
  // ---- memset region (zeroed every launch) ----
  u32* hist    = (u32*)alloc((size_t)BB * BINS * 4);    // 128 KB
  u32* rank    = (u32*)alloc((size_t)BB * SELCAP * 4);  // 96 KB
  u32* selctr  = (u32*)alloc((size_t)BB * 4);
  u32* edgecnt = (u32*)alloc((size_t)BB * 4);
  const size_t zbytes = off;
  // ---- rest ----
  u32* ord     = (u32*)alloc((size_t)BB * NN * 4);      // 256 KB
  u32* bstar   = (u32*)alloc((size_t)BB * 4);
  u64* candkey = (u64*)alloc((size_t)BB * SELCAP * 8);  // 192 KB
  u32* sidx    = (u32*)alloc((size_t)BB * PRE * 4);
  float4* bx4  = (float4*)alloc((size_t)BB * PRE * 16);
  float* ar    = (float*)alloc((size_t)BB * PRE * 4);
  float* gsc   = (float*)alloc((size_t)BB * PRE * 4);
  u32* glab    = (u32*)alloc((size_t)BB * PRE * 4);
  u32* edges   = (u32*)alloc((size_t)BB * ECAP * 4);    // 32 KB

  hipMemsetAsync(ws, 0, zbytes, stream);  // hist + rank + selctr + edgecnt

  hipLaunchKernelGGL(hist_kernel, dim3(BB * NN / 1024), dim3(1024), 0, stream,
                     cls, ord, hist);
  hipLaunchKernelGGL(bstar_kernel, dim3(BB), dim3(1024), 0, stream, hist, bstar);
  hipLaunchKernelGGL(compact_kernel, dim3(BB * 16), dim3(1024), 0, stream,
                     ord, bstar, selctr, candkey);
  hipLaunchKernelGGL(rank_kernel, dim3(BB * NTC * NCH), dim3(256), 0, stream,
                     selctr, candkey, rank);
  hipLaunchKernelGGL(scatter_kernel, dim3(BB * SELCAP / 256), dim3(256), 0, stream,
                     box, cls, selctr, candkey, rank, sidx, bx4, ar, gsc, glab);
  hipLaunchKernelGGL(pairs_kernel, dim3(BB * NTRI), dim3(256), 0, stream,
                     bx4, ar, edgecnt, edges);
  hipLaunchKernelGGL(nms_kernel, dim3(BB), dim3(256), 0, stream,
                     box, gt, sidx, gsc, glab, edgecnt, edges, out);
}

// Round 8
// 129.993 us; speedup vs baseline: 4.0737x; 1.1592x over previous
//
#include <hip/hip_runtime.h>
#include <cstdint>
#include <cstddef>

#define BB 4
#define NN 16384
#define PRE 4096
#define POST 512
#define SELCAP 6144   // C = 4096 + one 13-bit bin (~500) << 6144
#define BINS 8192     // top-13 bits of f32 ordinal
#define NTRI 2080     // 64*65/2 upper-tri tiles for pairs
#define RTILE 1024    // candidates per rank block (256 thr x 4)
#define RCHUNK 512    // keys per rank block chunk
#define NTC (SELCAP / RTILE)   // 6
#define NCH (SELCAP / RCHUNK)  // 12
#define ECAP 2048     // per-batch edge cap (expected E ~ tens)

typedef unsigned short u16;
typedef unsigned int u32;
typedef unsigned long long u64;

// monotone map: f32 bits -> u32 ordinal preserving float order
__device__ __forceinline__ u32 ord32(float f) {
  u32 u = __builtin_bit_cast(u32, f);
  return (u & 0x80000000u) ? ~u : (u | 0x80000000u);
}

// ---- K1: fused per-batch: zero rank/selctr/edgecnt, score->ord, LDS hist, B* ----
__global__ __launch_bounds__(1024) void histbstar_kernel(const float* __restrict__ cls,
                                                         u32* __restrict__ ord,
                                                         u32* __restrict__ bstar,
                                                         u32* __restrict__ selctr,
                                                         u32* __restrict__ edgecnt,
                                                         u32* __restrict__ rank) {
  __shared__ u32 hist[BINS];   // 32 KB
  __shared__ u32 orig[1024];
  __shared__ u32 bufA[1024];
  __shared__ u32 bufB[1024];   // +12 KB
  __shared__ int bs;
  const int b = blockIdx.x, t = threadIdx.x;
  for (int p = t; p < BINS; p += 1024) hist[p] = 0u;
  if (t == 0) { bs = 0; selctr[b] = 0u; edgecnt[b] = 0u; }
  for (int p = t; p < SELCAP; p += 1024) rank[b * SELCAP + p] = 0u;
  __syncthreads();
  const float* c = cls + (size_t)b * NN * 3;
  for (int n = t; n < NN; n += 1024) {
    float s = fmaxf(fmaxf(c[n * 3], c[n * 3 + 1]), c[n * 3 + 2]);
    u32 o = ord32(s);
    ord[b * NN + n] = o;
    atomicAdd(&hist[o >> 19], 1u);
  }
  __syncthreads();
  u32 s = 0;
#pragma unroll
  for (int j = 0; j < 8; ++j) s += hist[t * 8 + j];
  orig[t] = s;
  bufA[t] = s;
  __syncthreads();
  u32* src = bufA;
  u32* dst = bufB;
  for (int off = 1; off < 1024; off <<= 1) {
    u32 v = src[t] + ((t + off < 1024) ? src[t + off] : 0u);
    dst[t] = v;
    __syncthreads();
    u32* tmp = src; src = dst; dst = tmp;
  }
  u32 running = src[t] - orig[t];  // items in bins above this chunk
  for (int j = 7; j >= 0; --j) {
    u32 v = hist[t * 8 + j];
    u32 nr = running + v;
    if (nr >= (u32)PRE && running < (u32)PRE) bs = t * 8 + j;  // unique crossing
    running = nr;
  }
  __syncthreads();
  if (t == 0) bstar[b] = (u32)bs;
}

// ---- K2: compact candidates — wave ballot + block aggregation ----
__global__ __launch_bounds__(1024) void compact_kernel(const u32* __restrict__ ord,
                                                       const u32* __restrict__ bstar,
                                                       u32* __restrict__ selctr,
                                                       u64* __restrict__ candkey) {
  __shared__ u32 wbase[16];
  __shared__ u32 bbase;
  const int b = blockIdx.x >> 4;    // 16 blocks per batch
  const int blk = blockIdx.x & 15;
  const int t = threadIdx.x;
  const int n = blk * 1024 + t;     // element within batch
  u32 o = ord[(b << 14) + n];
  bool pred = (o >> 19) >= bstar[b];
  u64 mask = __ballot(pred);
  int lane = t & 63, w = t >> 6;
  if (lane == 0) wbase[w] = (u32)__popcll(mask);
  u32 lpre = (u32)__popcll(mask & ((lane == 0) ? 0ull : (~0ull >> (64 - lane))));
  __syncthreads();
  if (t == 0) {
    u32 s = 0;
#pragma unroll
    for (int i = 0; i < 16; ++i) { u32 v = wbase[i]; wbase[i] = s; s += v; }
    bbase = atomicAdd(&selctr[b], s);  // ONE global atomic per block
  }
  __syncthreads();
  if (pred) {
    u32 pos = bbase + wbase[w] + lpre;
    if (pos < SELCAP)
      candkey[(size_t)b * SELCAP + pos] = ((u64)o << 14) | (u64)(NN - 1 - n);  // score desc, idx asc
  }
}

// ---- K3: partial rank-by-counting, key-chunk split, LDS-staged ----
__global__ __launch_bounds__(256) void rank_kernel(const u32* __restrict__ selctr,
                                                   const u64* __restrict__ candkey,
                                                   u32* __restrict__ rank) {
  __shared__ u64 sk[RCHUNK];  // 4 KB
  const int bid = blockIdx.x;
  const int b = bid / (NTC * NCH);
  const int rem = bid % (NTC * NCH);
  const int ct = rem / NCH, kc = rem % NCH;
  u32 C = selctr[b];
  if (C > SELCAP) C = SELCAP;
  const int kbase = kc * RCHUNK;
  const int cbase = ct * RTILE;
  if ((u32)kbase >= C || (u32)cbase >= C) return;
  const u64* __restrict__ ck = candkey + (size_t)b * SELCAP;
  const int t = threadIdx.x;
  for (int s = t; s < RCHUNK; s += 256) {
    int slot = kbase + s;
    sk[s] = (slot < (int)C) ? ck[slot] : 0ull;  // 0 < any real key
  }
  __syncthreads();
  u64 my[4];
  u32 r[4] = {0u, 0u, 0u, 0u};
#pragma unroll
  for (int a = 0; a < 4; ++a) {
    int cand = cbase + a * 256 + t;
    my[a] = (cand < (int)C) ? ck[cand] : ~0ull;  // ~0: nothing greater
  }
  const int kn = min((int)C - kbase, RCHUNK);
  int k = 0;
  for (; k + 4 <= kn; k += 4) {
    u64 k0 = sk[k], k1 = sk[k + 1], k2 = sk[k + 2], k3 = sk[k + 3];
#pragma unroll
    for (int a = 0; a < 4; ++a)
      r[a] += (u32)(k0 > my[a]) + (u32)(k1 > my[a]) + (u32)(k2 > my[a]) + (u32)(k3 > my[a]);
  }
  for (; k < kn; ++k) {
    u64 kv = sk[k];
#pragma unroll
    for (int a = 0; a < 4; ++a) r[a] += (u32)(kv > my[a]);
  }
#pragma unroll
  for (int a = 0; a < 4; ++a) {
    int cand = cbase + a * 256 + t;
    if (cand < (int)C && r[a] > 0u)
      atomicAdd(&rank[(size_t)b * SELCAP + cand], r[a]);
  }
}

// ---- K4: scatter by final rank + fused geometry gather ----
__global__ __launch_bounds__(256) void scatter_kernel(
    const float* __restrict__ box, const float* __restrict__ cls,
    const u32* __restrict__ selctr, const u64* __restrict__ candkey,
    const u32* __restrict__ rank,
    u32* __restrict__ sidx, float4* __restrict__ bx4, float* __restrict__ ar,
    float* __restrict__ gsc, u32* __restrict__ glab) {
  const int gg = blockIdx.x * 256 + threadIdx.x;
  if (gg >= BB * SELCAP) return;
  const int b = gg / SELCAP, cand = gg % SELCAP;
  u32 C = selctr[b];
  if (C > SELCAP) C = SELCAP;
  if (cand >= (int)C) return;
  const u32 r = rank[gg];
  if (r >= (u32)PRE) return;
  const u64 mykey = candkey[(size_t)b * SELCAP + cand];
  const int idx = (NN - 1) - (int)(mykey & 0x3FFFull);
  const int g = (b << 12) + (int)r;
  sidx[g] = (u32)idx;
  const float* bp = box + ((size_t)(b << 14) + idx) * 7;
  float x = bp[0], y = bp[1];
  float dx = bp[3], dy = bp[4];
  float4 v;
  v.x = x - dx * 0.5f;   // x1
  v.y = x + dx * 0.5f;   // x2
  v.z = y - dy * 0.5f;   // y1
  v.w = y + dy * 0.5f;   // y2
  bx4[g] = v;
  ar[g] = dx * dy;
  const float* cp = cls + ((size_t)(b << 14) + idx) * 3;
  float f0 = cp[0], f1 = cp[1], f2 = cp[2];
  int lab = 0;
  float best = f0;
  if (f1 > best) { best = f1; lab = 1; }
  if (f2 > best) { best = f2; lab = 2; }
  gsc[g] = best;
  glab[g] = (u32)lab;
}

// ---- K5: sparse edges (i<j, IoU>0.8) -> compact per-batch edge list ----
__global__ __launch_bounds__(256) void pairs_kernel(const float4* __restrict__ bx4,
                                                    const float* __restrict__ ar,
                                                    u32* __restrict__ edgecnt,
                                                    u32* __restrict__ edges) {
  __shared__ float4 si4[64], sj4[64];
  __shared__ float sia[64], sja[64];
  const int bid = blockIdx.x;
  const int b = bid / NTRI;
  const int rr = bid % NTRI;
  // decode upper-tri tile (ti<=tj) from reversed triangular index
  int m = NTRI - 1 - rr;
  int q = (int)((sqrtf(8.0f * (float)m + 1.0f) - 1.0f) * 0.5f);
  while ((q + 1) * (q + 2) / 2 <= m) ++q;
  while (q * (q + 1) / 2 > m) --q;
  int p = m - q * (q + 1) / 2;
  const int ti = 63 - q, tj = 63 - q + p;  // ti <= tj
  const int tid = threadIdx.x;
  const int base = b << 12;
  if (tid < 64) {
    si4[tid] = bx4[base + ti * 64 + tid];
    sia[tid] = ar[base + ti * 64 + tid];
  } else if (tid < 128) {
    int l = tid - 64;
    sj4[l] = bx4[base + tj * 64 + l];
    sja[l] = ar[base + tj * 64 + l];
  }
  __syncthreads();
  const int i0 = (tid & 15) * 4, j0 = (tid >> 4) * 4;
  float4 A[4], Bv[4];
  float Aa[4], Ba[4];
#pragma unroll
  for (int a = 0; a < 4; ++a) { A[a] = si4[i0 + a]; Aa[a] = sia[i0 + a]; }
#pragma unroll
  for (int c = 0; c < 4; ++c) { Bv[c] = sj4[j0 + c]; Ba[c] = sja[j0 + c]; }
#pragma unroll
  for (int a = 0; a < 4; ++a) {
#pragma unroll
    for (int c = 0; c < 4; ++c) {
      const int i = ti * 64 + i0 + a;
      const int j = tj * 64 + j0 + c;
      if (j <= i) continue;  // upper triangle within diag tile
      float ix = fminf(A[a].y, Bv[c].y) - fmaxf(A[a].x, Bv[c].x);
      ix = fmaxf(ix, 0.0f);
      float iy = fminf(A[a].w, Bv[c].w) - fmaxf(A[a].z, Bv[c].z);
      iy = fmaxf(iy, 0.0f);
      float inter = ix * iy;
      float denom = ((Aa[a] + Ba[c]) - inter) + 1e-6f;  // np op order
      float iou = inter / denom;                        // IEEE f32 div
      if (iou > 0.8f) {                                 // rare (~tens per batch)
        u32 pos = atomicAdd(&edgecnt[b], 1u);
        if (pos < ECAP) edges[(b << 11) + pos] = ((u32)i << 12) | (u32)j;
      }
    }
  }
}

// ---- K6: edge-driven NMS resolution (E iters, not 512) + all outputs (f32) ----
__global__ __launch_bounds__(256) void nms_kernel(
    const float* __restrict__ box, const float* __restrict__ gt,
    const u32* __restrict__ sidx, const float* __restrict__ gsc,
    const u32* __restrict__ glab, const u32* __restrict__ edgecnt,
    const u32* __restrict__ edges, float* __restrict__ out) {
  __shared__ u32 sedge[ECAP];   // 8 KB
  __shared__ u32 ssort[ECAP];   // 8 KB
  __shared__ u64 ssup[64];
  __shared__ u32 spop[65];
  __shared__ u16 ssel[POST];
  __shared__ u16 skeep[POST];
  const int b = blockIdx.x, tid = threadIdx.x;
  int E = (int)edgecnt[b];
  if (E > ECAP) E = ECAP;
  if (tid < 64) ssup[tid] = 0ull;
  for (int e = tid; e < E; e += 256) sedge[e] = edges[(b << 11) + e];
  for (int t2 = tid; t2 < POST; t2 += 256) ssel[t2] = 0;
  __syncthreads();
  // sort edges ascending by (i<<12|j) — unique keys, rank-by-count
  for (int e = tid; e < E; e += 256) {
    u32 key = sedge[e];
    u32 r = 0;
    for (int k = 0; k < E; ++k) r += (u32)(sedge[k] < key);
    ssort[r] = key;
  }
  __syncthreads();
  // forward resolution in source-index order (equiv. to untruncated greedy scan)
  if (tid == 0) {
    for (int e = 0; e < E; ++e) {
      u32 v = ssort[e];
      u32 i = v >> 12, j = v & 4095u;
      if (!((ssup[i >> 6] >> (i & 63u)) & 1ull)) ssup[j >> 6] |= (1ull << (j & 63u));
    }
  }
  __syncthreads();
  if (tid < 64) spop[tid] = (u32)__popcll(~ssup[tid]);
  __syncthreads();
  if (tid == 0) {
    u32 acc = 0;
    for (int w = 0; w < 64; ++w) { u32 v = spop[w]; spop[w] = acc; acc += v; }
    spop[64] = acc;
  }
  __syncthreads();
  const int ns = (int)spop[64];
  if (tid < 64) {
    u64 w = ~ssup[tid];
    u32 base2 = spop[tid];
    while (w) {
      int bit = __ffsll((unsigned long long)w) - 1;
      w &= w - 1;
      if (base2 >= (u32)POST) break;
      ssel[base2] = (u16)((tid << 6) + bit);
      ++base2;
    }
  }
  for (int t2 = tid; t2 < POST; t2 += 256) skeep[t2] = (t2 < ns) ? (u16)1 : (u16)0;
  __syncthreads();

  float* rois = out;                  // B*POST*7
  float* rsc  = out + BB * POST * 7;  // B*POST
  float* rlb  = rsc + BB * POST;      // B*POST
  float* rct  = rlb + BB * POST;      // B*POST*8

  const float TWO_PI_F = 6.283185307179586f;
  const float PI_F = 3.14159265358979323846f;
  const float HALF_PI_F = 1.5707963267948966f;
  const float THREE_HALF_PI_F = 4.71238898038469f;

  for (int t = tid; t < POST; t += 256) {
    int i = ssel[t];
    int kp = skeep[t];
    int g = (b << 12) + i;
    u32 idx = sidx[g];
    const float* bp = box + ((size_t)(b << 14) + idx) * 7;
    float bx[7];
#pragma unroll
    for (int d = 0; d < 7; ++d) bx[d] = kp ? bp[d] : 0.0f;
    float* ro = rois + ((size_t)b * POST + t) * 7;
#pragma unroll
    for (int d = 0; d < 7; ++d) ro[d] = bx[d];
    rsc[b * POST + t] = kp ? gsc[g] : 0.0f;
    rlb[b * POST + t] = (float)((kp ? (int)glab[g] : 0) + 1);

    // canonical transform in f32, matching np op order
    const float* gp = gt + ((size_t)b * POST + t) * 8;
    float g0 = gp[0], g1 = gp[1], g2 = gp[2], g6 = gp[6];
    float rr = fmodf(bx[6], TWO_PI_F);
    if (rr < 0.0f) rr += TWO_PI_F;
    float xyz0 = g0 - bx[0], xyz1 = g1 - bx[1], xyz2 = g2 - bx[2];
    float heading = g6 - rr;
    float aa = -rr;
    float cc = cosf(aa), s2 = sinf(aa);
    float nx = xyz0 * cc - xyz1 * s2;
    float ny = xyz0 * s2 + xyz1 * cc;
    float h = fmodf(heading, TWO_PI_F);
    if (h < 0.0f) h += TWO_PI_F;
    bool opp = (h > HALF_PI_F) && (h < THREE_HALF_PI_F);
    if (opp) {
      h = fmodf(h + PI_F, TWO_PI_F);
      if (h < 0.0f) h += TWO_PI_F;
    }
    if (h > PI_F) h -= TWO_PI_F;
    h = fminf(fmaxf(h, -HALF_PI_F), HALF_PI_F);

    float* co = rct + ((size_t)b * POST + t) * 8;
    co[0] = nx;
    co[1] = ny;
    co[2] = xyz2;
    co[3] = gp[3];
    co[4] = gp[4];
    co[5] = gp[5];
    co[6] = h;
    co[7] = gp[7];
  }
}

extern "C" void kernel_launch(void* const* d_in, const int* in_sizes, int n_in,
                              void* d_out, int out_size, void* d_ws, size_t ws_size,
                              hipStream_t stream) {
  const float* box = (const float*)d_in[0];  // (B,N,7) f32
  const float* cls = (const float*)d_in[1];  // (B,N,3) f32
  const float* gt  = (const float*)d_in[2];  // (B,POST,8) f32
  float* out = (float*)d_out;                // 34816 f32, concat in return order

  char* ws = (char*)d_ws;
  size_t off = 0;
  auto alloc = [&](size_t bytes) -> void* {
    void* p = ws + off;
    off += (bytes + 255) & ~(size_t)255;
    return p;
  };
  u32* rank    = (u32*)alloc((size_t)BB * SELCAP * 4);  // 96 KB
  u32* selctr  = (u32*)alloc((size_t)BB * 4);
  u32* edgecnt = (u32*)alloc((size_t)BB * 4);
  u32* ord     = (u32*)alloc((size_t)BB * NN * 4);      // 256 KB
  u32* bstar   = (u32*)alloc((size_t)BB * 4);
  u64* candkey = (u64*)alloc((size_t)BB * SELCAP * 8);  // 192 KB
  u32* sidx    = (u32*)alloc((size_t)BB * PRE * 4);
  float4* bx4  = (float4*)alloc((size_t)BB * PRE * 16);
  float* ar    = (float*)alloc((size_t)BB * PRE * 4);
  float* gsc   = (float*)alloc((size_t)BB * PRE * 4);
  u32* glab    = (u32*)alloc((size_t)BB * PRE * 4);
  u32* edges   = (u32*)alloc((size_t)BB * ECAP * 4);    // 32 KB

  hipLaunchKernelGGL(histbstar_kernel, dim3(BB), dim3(1024), 0, stream,
                     cls, ord, bstar, selctr, edgecnt, rank);
  hipLaunchKernelGGL(compact_kernel, dim3(BB * 16), dim3(1024), 0, stream,
                     ord, bstar, selctr, candkey);
  hipLaunchKernelGGL(rank_kernel, dim3(BB * NTC * NCH), dim3(256), 0, stream,
                     selctr, candkey, rank);
  hipLaunchKernelGGL(scatter_kernel, dim3(BB * SELCAP / 256), dim3(256), 0, stream,
                     box, cls, selctr, candkey, rank, sidx, bx4, ar, gsc, glab);
  hipLaunchKernelGGL(pairs_kernel, dim3(BB * NTRI), dim3(256), 0, stream,
                     bx4, ar, edgecnt, edges);
  hipLaunchKernelGGL(nms_kernel, dim3(BB), dim3(256), 0, stream,
                     box, gt, sidx, gsc, glab, edgecnt, edges, out);
}